// Round 19
// baseline (147.550 us; speedup 1.0000x reference)
//
#include <hip/hip_runtime.h>
#include <hip/hip_bf16.h>

#define NQ   14
#define DIM  16384      // 2^14
#define BLK  1024
#define WMUL 0.6324555320336759f  // sqrt(2/5)

typedef float v2f __attribute__((ext_vector_type(2)));

struct C2 { float x, y; };  // build-time only
__device__ inline C2 cmulc(C2 a, C2 b){ return C2{a.x*b.x - a.y*b.y, a.x*b.y + a.y*b.x}; }
__device__ inline C2 caddc(C2 a, C2 b){ return C2{a.x+b.x, a.y+b.y}; }
__device__ inline void mm2(const C2* a, const C2* b, C2* o) {
    o[0] = caddc(cmulc(a[0],b[0]), cmulc(a[1],b[2]));
    o[1] = caddc(cmulc(a[0],b[1]), cmulc(a[1],b[3]));
    o[2] = caddc(cmulc(a[2],b[0]), cmulc(a[3],b[2]));
    o[3] = caddc(cmulc(a[2],b[1]), cmulc(a[3],b[3]));
}
__device__ inline void build_gate(int ty, float t, C2* g) {
    float sn, cs;
    __sincosf(0.5f * t, &sn, &cs);
    if (ty == 0) {        // rx
        g[0] = C2{cs, 0.f}; g[1] = C2{0.f, -sn};
        g[2] = C2{0.f, -sn}; g[3] = C2{cs, 0.f};
    } else if (ty == 1) { // ry
        g[0] = C2{cs, 0.f}; g[1] = C2{-sn, 0.f};
        g[2] = C2{sn, 0.f}; g[3] = C2{cs, 0.f};
    } else {              // rz
        g[0] = C2{cs, -sn}; g[1] = C2{0.f, 0.f};
        g[2] = C2{0.f, 0.f}; g[3] = C2{cs, sn};
    }
}
__device__ const int TYPES[5][3] = {
    {0,1,2},  // XYZ
    {1,2,1},  // YZY
    {2,1,0},  // ZYX
    {0,2,0},  // XZX
    {1,2,1},  // YZY
};

// ---- prep kernel: 70 fused gates (row-major floats) + observable -> d_ws ----
// gate k at gg[k*8 + {0..7}] = {M00.x,M00.y, M01.x,M01.y, M10.x,M10.y, M11.x,M11.y}
__global__ void prep_kernel(const float* __restrict__ w, float* __restrict__ gg) {
    const int tid = threadIdx.x;
    if (tid < 5 * NQ) {
        const int li = tid / NQ, q = tid % NQ;
        C2 M[4], G[4], T[4];
        #pragma unroll
        for (int j = 0; j < 3; ++j) {
            float t = w[3 * NQ * li + 3 * q + j] * WMUL;
            build_gate(TYPES[li][j], t, G);
            if (j == 0) { M[0]=G[0]; M[1]=G[1]; M[2]=G[2]; M[3]=G[3]; }
            else { mm2(G, M, T); M[0]=T[0]; M[1]=T[1]; M[2]=T[2]; M[3]=T[3]; }
        }
        float* gb = &gg[tid * 8];
        #pragma unroll
        for (int k = 0; k < 4; ++k) { gb[k*2] = M[k].x; gb[k*2+1] = M[k].y; }
        // absorbed observable M1 = M† Z M for the layer-5 qubit-0 rotation
        if (tid == 4 * NQ + 0) {
            float* mm = &gg[5 * NQ * 8];
            mm[0] = M[0].x*M[0].x + M[0].y*M[0].y - (M[2].x*M[2].x + M[2].y*M[2].y);
            mm[1] = M[1].x*M[1].x + M[1].y*M[1].y - (M[3].x*M[3].x + M[3].y*M[3].y);
            mm[2] = (M[0].x*M[1].x + M[0].y*M[1].y) - (M[2].x*M[3].x + M[2].y*M[3].y);
            mm[3] = (M[0].x*M[1].y - M[0].y*M[1].x) - (M[2].x*M[3].y - M[2].y*M[3].x);
        }
    }
}

// bank-conflict swizzle; GF(2)-LINEAR: slotf(a|b) = slotf(a)^slotf(b) for disjoint a,b
__device__ inline constexpr uint32_t slotf(uint32_t i){
    return i ^ (((i>>4) ^ (i>>8) ^ (i>>12)) & 15u);
}
template<int B> __device__ inline constexpr uint32_t ins0(uint32_t t){
    return ((t & ~((1u<<B)-1u)) << 1) | (t & ((1u<<B)-1u));
}
template<int B0,int B1,int B2> __device__ inline constexpr uint32_t expand3(uint32_t t){
    return ins0<B2>(ins0<B1>(ins0<B0>(t)));
}
template<int B0,int B1,int B2> __device__ inline constexpr uint32_t rmask3(int r){
    return ((r&1)?(1u<<B0):0u) | ((r&2)?(1u<<B1):0u) | ((r&4)?(1u<<B2):0u);
}

// Packed rotation on local bit J over slab-SoA state: vre/vim[8], v2f lanes =
// (slab0, slab1). Pure elementwise math with scalar-broadcast coefficients:
// NO shuffles -> clang emits v_pk_fma_f32. 16 pk ops per pair (both slabs).
template<int J>
__device__ inline void rotP(v2f* vre, v2f* vim, const float* __restrict__ g){
    const float are=g[0], aim=g[1], bre=g[2], bim=g[3];
    const float cre=g[4], cim=g[5], dre=g[6], dim=g[7];
    #pragma unroll
    for (int r = 0; r < 8; ++r){
        if (!(r & (1 << J))) {
            const int r1 = r | (1 << J);
            v2f x0r = vre[r],  x0i = vim[r];
            v2f x1r = vre[r1], x1i = vim[r1];
            vre[r]  = are*x0r - aim*x0i + bre*x1r - bim*x1i;
            vim[r]  = are*x0i + aim*x0r + bre*x1i + bim*x1r;
            vre[r1] = cre*x0r - cim*x0i + dre*x1r - dim*x1i;
            vim[r1] = cre*x0i + cim*x0r + dre*x1i + dim*x1r;
        }
    }
}
// CNOT both-in-reg: pure register renaming on both planes
template<int C, int T>
__device__ inline void cnotP(v2f* vre, v2f* vim){
    #pragma unroll
    for (int r = 0; r < 8; ++r){
        if ((r & (1 << C)) && !(r & (1 << T))) {
            const int r1 = r | (1 << T);
            v2f t0 = vre[r]; vre[r] = vre[r1]; vre[r1] = t0;
            v2f t1 = vim[r]; vim[r] = vim[r1]; vim[r1] = t1;
        }
    }
}
// CNOT with control = tid bit (same for both slabs), target reg bit T
template<int T>
__device__ inline void cnotSelP(v2f* vre, v2f* vim, bool c){
    #pragma unroll
    for (int r = 0; r < 8; ++r){
        if (!(r & (1 << T))) {
            const int r1 = r | (1 << T);
            v2f lo0 = vre[r], hi0 = vre[r1];
            v2f lo1 = vim[r], hi1 = vim[r1];
            vre[r] = c ? hi0 : lo0;  vre[r1] = c ? lo0 : hi0;
            vim[r] = c ? hi1 : lo1;  vim[r1] = c ? lo1 : hi1;
        }
    }
}

__global__ __launch_bounds__(BLK) void qsim_kernel(
        const float* __restrict__ xr, const float* __restrict__ xi,
        const float* __restrict__ gg, float* __restrict__ out) {
    __shared__ v2f s[DIM];            // 128 KiB statevector, AoS (re,im), swizzled
    __shared__ float red[BLK / 64];

    const int b   = blockIdx.x;
    const uint32_t tid = threadIdx.x;

    const float* xrb = xr + (size_t)b * DIM;
    const float* xib = xi + (size_t)b * DIM;

    // qubit q <-> bit (13-q).  coefficients: uniform global (prep kernel output)
    #define GMP(li, q) (&gg[((li) * NQ + (q)) * 8])

    // One pass: both slabs in one sweep via slab-SoA registers.
    // sbB = sbA ^ const (expand3 is bit-deposit-linear; tid<1024 so +BLK = |bit10)
    #define PASS(X0, X1, X2, ...)                                                  \
        {                                                                          \
            const uint32_t sbA = slotf(expand3<X0,X1,X2>(tid));                    \
            const uint32_t sbB = sbA ^ slotf(expand3<X0,X1,X2>((uint32_t)BLK));    \
            v2f vre[8], vim[8];                                                    \
            _Pragma("unroll")                                                      \
            for (int r = 0; r < 8; ++r) {                                          \
                v2f qa = s[sbA ^ slotf(rmask3<X0,X1,X2>(r))];                      \
                v2f qb = s[sbB ^ slotf(rmask3<X0,X1,X2>(r))];                      \
                vre[r] = v2f{qa.x, qb.x}; vim[r] = v2f{qa.y, qb.y};                \
            }                                                                      \
            __VA_ARGS__                                                            \
            _Pragma("unroll")                                                      \
            for (int r = 0; r < 8; ++r) {                                          \
                s[sbA ^ slotf(rmask3<X0,X1,X2>(r))] = v2f{vre[r].x, vim[r].x};     \
                s[sbB ^ slotf(rmask3<X0,X1,X2>(r))] = v2f{vre[r].y, vim[r].y};     \
            }                                                                      \
        }                                                                          \
        __syncthreads();

    float local = 0.f;

    // ---- 4 ring layers, 5 non-overlapping windows each; L5 absorbed in meas ----
    // A(11,12,13): rot q0,q1,q2 + CN(0,1),(1,2)
    // B(8,9,10):   rot q3,q4,q5 + CN(2,3)[sel ctl=t8] + CN(3,4),(4,5)
    // C(5,6,7):    rot q6,q7,q8 + CN(5,6)[sel ctl=t5] + CN(6,7),(7,8)
    // D(2,3,4):    rot q9,q10,q11 + CN(8,9)[sel ctl=t2] + CN(9,10),(10,11)
    // E(0,1,13):   rot q12,q13 + CN(11,12)[sel ctl=t0] + CN(12,13),(13,0)
    //              (li==3: fuse M1 quadratic form on b13 = L2 pairs, no scatter)
    #pragma unroll 1
    for (int li = 0; li < 4; ++li) {
        // ---- A (11,12,13) ----
        {
            const uint32_t sbA = slotf(expand3<11,12,13>(tid));
            const uint32_t sbB = sbA ^ slotf(expand3<11,12,13>((uint32_t)BLK));
            v2f vre[8], vim[8];
            if (li == 0) {
                // global is already SoA: direct packed load, no shuffles
                #pragma unroll
                for (int r = 0; r < 8; ++r) {
                    uint32_t iA = tid | ((uint32_t)r << 11);   // expand3<11,12,13>(t)=t
                    uint32_t iB = iA | BLK;                    // slab bit = b10
                    vre[r] = v2f{xrb[iA], xrb[iB]};
                    vim[r] = v2f{xib[iA], xib[iB]};
                }
            } else {
                #pragma unroll
                for (int r = 0; r < 8; ++r) {
                    v2f qa = s[sbA ^ slotf(rmask3<11,12,13>(r))];
                    v2f qb = s[sbB ^ slotf(rmask3<11,12,13>(r))];
                    vre[r] = v2f{qa.x, qb.x}; vim[r] = v2f{qa.y, qb.y};
                }
            }
            rotP<2>(vre, vim, GMP(li,0));
            rotP<1>(vre, vim, GMP(li,1));
            rotP<0>(vre, vim, GMP(li,2));
            cnotP<2,1>(vre, vim); cnotP<1,0>(vre, vim);    // CN(0,1),(1,2)
            #pragma unroll
            for (int r = 0; r < 8; ++r) {
                s[sbA ^ slotf(rmask3<11,12,13>(r))] = v2f{vre[r].x, vim[r].x};
                s[sbB ^ slotf(rmask3<11,12,13>(r))] = v2f{vre[r].y, vim[r].y};
            }
        }
        __syncthreads();

        // ---- B (8,9,10): rot q3(b10),q4(b9),q5(b8) ----
        PASS(8,9,10,
            rotP<2>(vre, vim, GMP(li,3));
            rotP<1>(vre, vim, GMP(li,4));
            rotP<0>(vre, vim, GMP(li,5));
            cnotSelP<2>(vre, vim, (tid >> 8) & 1u);        // CN(2,3): ctl q2=b11
            cnotP<2,1>(vre, vim); cnotP<1,0>(vre, vim);    // CN(3,4),(4,5)
        )
        // ---- C (5,6,7): rot q6(b7),q7(b6),q8(b5) ----
        PASS(5,6,7,
            rotP<2>(vre, vim, GMP(li,6));
            rotP<1>(vre, vim, GMP(li,7));
            rotP<0>(vre, vim, GMP(li,8));
            cnotSelP<2>(vre, vim, (tid >> 5) & 1u);        // CN(5,6): ctl q5=b8
            cnotP<2,1>(vre, vim); cnotP<1,0>(vre, vim);    // CN(6,7),(7,8)
        )
        // ---- D (2,3,4): rot q9(b4),q10(b3),q11(b2) ----
        PASS(2,3,4,
            rotP<2>(vre, vim, GMP(li,9));
            rotP<1>(vre, vim, GMP(li,10));
            rotP<0>(vre, vim, GMP(li,11));
            cnotSelP<2>(vre, vim, (tid >> 2) & 1u);        // CN(8,9): ctl q8=b5
            cnotP<2,1>(vre, vim); cnotP<1,0>(vre, vim);    // CN(9,10),(10,11)
        )
        // ---- E (0,1,13): rot q12(b1=L1),q13(b0=L0) ----
        {
            const uint32_t sbA = slotf(expand3<0,1,13>(tid));
            const uint32_t sbB = sbA ^ slotf(expand3<0,1,13>((uint32_t)BLK));
            v2f vre[8], vim[8];
            #pragma unroll
            for (int r = 0; r < 8; ++r) {
                v2f qa = s[sbA ^ slotf(rmask3<0,1,13>(r))];
                v2f qb = s[sbB ^ slotf(rmask3<0,1,13>(r))];
                vre[r] = v2f{qa.x, qb.x}; vim[r] = v2f{qa.y, qb.y};
            }
            rotP<1>(vre, vim, GMP(li,12));
            rotP<0>(vre, vim, GMP(li,13));
            cnotSelP<1>(vre, vim, tid & 1u);               // CN(11,12): ctl q11=b2
            cnotP<1,0>(vre, vim);                          // CN(12,13)
            cnotP<0,2>(vre, vim);                          // CN(13,0)
            if (li < 3) {
                #pragma unroll
                for (int r = 0; r < 8; ++r) {
                    s[sbA ^ slotf(rmask3<0,1,13>(r))] = v2f{vre[r].x, vim[r].x};
                    s[sbB ^ slotf(rmask3<0,1,13>(r))] = v2f{vre[r].y, vim[r].y};
                }
            } else {
                const float* mm = &gg[5 * NQ * 8];
                const float mA = mm[0], mB = mm[1], mP = mm[2], mQ = mm[3];
                v2f acc = v2f{0.f, 0.f};
                #pragma unroll
                for (int r = 0; r < 4; ++r) {
                    const int r1 = r | 4;                  // b13=1 partner
                    v2f x0r = vre[r],  x0i = vim[r];
                    v2f x1r = vre[r1], x1i = vim[r1];
                    v2f n0 = x0r*x0r + x0i*x0i;
                    v2f n1 = x1r*x1r + x1i*x1i;
                    v2f u  = x0r*x1r + x0i*x1i;            // Re(conj(a0) a1)
                    v2f vv = x0r*x1i - x0i*x1r;            // Im(conj(a0) a1)
                    acc += mA*n0 + mB*n1 + 2.f*(mP*u - mQ*vv);
                }
                local += acc.x + acc.y;
            }
        }
        if (li < 3) __syncthreads();
    }

    #pragma unroll
    for (int off = 32; off > 0; off >>= 1) local += __shfl_down(local, off);
    const int lane = tid & 63, wid = tid >> 6;
    if (lane == 0) red[wid] = local;
    __syncthreads();
    if (tid == 0) {
        float t = 0.f;
        #pragma unroll
        for (int k = 0; k < BLK / 64; ++k) t += red[k];
        out[b] = t;
    }
}

extern "C" void kernel_launch(void* const* d_in, const int* in_sizes, int n_in,
                              void* d_out, int out_size, void* d_ws, size_t ws_size,
                              hipStream_t stream) {
    const float* xr = (const float*)d_in[0];
    const float* xi = (const float*)d_in[1];
    const float* w  = (const float*)d_in[2];
    float* out = (float*)d_out;
    float* gg = (float*)d_ws;   // 70 gates x 8 floats + 4 floats meas = 2256 B
    const int B = out_size;     // 512
    prep_kernel<<<1, 128, 0, stream>>>(w, gg);
    qsim_kernel<<<B, BLK, 0, stream>>>(xr, xi, gg, out);
}

// Round 20
// 127.080 us; speedup vs baseline: 1.1611x; 1.1611x over previous
//
#include <hip/hip_runtime.h>

#define NQ   14
#define DIM  16384      // 2^14
#define HDIM 8192       // 2^13 (idx space; lane = bit b0 = qubit 13)
#define BLK  1024
#define WMUL 0.6324555320336759f  // sqrt(2/5)

typedef float v2f __attribute__((ext_vector_type(2)));

struct C2 { float x, y; };  // build-time only
__device__ inline C2 cmulc(C2 a, C2 b){ return C2{a.x*b.x - a.y*b.y, a.x*b.y + a.y*b.x}; }
__device__ inline C2 caddc(C2 a, C2 b){ return C2{a.x+b.x, a.y+b.y}; }
__device__ inline void mm2(const C2* a, const C2* b, C2* o) {
    o[0] = caddc(cmulc(a[0],b[0]), cmulc(a[1],b[2]));
    o[1] = caddc(cmulc(a[0],b[1]), cmulc(a[1],b[3]));
    o[2] = caddc(cmulc(a[2],b[0]), cmulc(a[3],b[2]));
    o[3] = caddc(cmulc(a[2],b[1]), cmulc(a[3],b[3]));
}
__device__ inline void build_gate(int ty, float t, C2* g) {
    float sn, cs;
    __sincosf(0.5f * t, &sn, &cs);
    if (ty == 0) {        // rx
        g[0] = C2{cs, 0.f}; g[1] = C2{0.f, -sn};
        g[2] = C2{0.f, -sn}; g[3] = C2{cs, 0.f};
    } else if (ty == 1) { // ry
        g[0] = C2{cs, 0.f}; g[1] = C2{-sn, 0.f};
        g[2] = C2{sn, 0.f}; g[3] = C2{cs, 0.f};
    } else {              // rz
        g[0] = C2{cs, -sn}; g[1] = C2{0.f, 0.f};
        g[2] = C2{0.f, 0.f}; g[3] = C2{cs, sn};
    }
}
__device__ const int TYPES[5][3] = {
    {0,1,2},  // XYZ
    {1,2,1},  // YZY
    {2,1,0},  // ZYX
    {0,2,0},  // XZX
    {1,2,1},  // YZY
};

// ---- prep kernel: 70 fused gates (row-major floats) + observable -> d_ws ----
// gate k at gg[k*8 + {0..7}] = {M00.x,M00.y, M01.x,M01.y, M10.x,M10.y, M11.x,M11.y}
__global__ void prep_kernel(const float* __restrict__ w, float* __restrict__ gg) {
    const int tid = threadIdx.x;
    if (tid < 5 * NQ) {
        const int li = tid / NQ, q = tid % NQ;
        C2 M[4], G[4], T[4];
        #pragma unroll
        for (int j = 0; j < 3; ++j) {
            float t = w[3 * NQ * li + 3 * q + j] * WMUL;
            build_gate(TYPES[li][j], t, G);
            if (j == 0) { M[0]=G[0]; M[1]=G[1]; M[2]=G[2]; M[3]=G[3]; }
            else { mm2(G, M, T); M[0]=T[0]; M[1]=T[1]; M[2]=T[2]; M[3]=T[3]; }
        }
        float* gb = &gg[tid * 8];
        #pragma unroll
        for (int k = 0; k < 4; ++k) { gb[k*2] = M[k].x; gb[k*2+1] = M[k].y; }
        // absorbed observable M1 = M† Z M for the layer-5 qubit-0 rotation
        if (tid == 4 * NQ + 0) {
            float* mm = &gg[5 * NQ * 8];
            mm[0] = M[0].x*M[0].x + M[0].y*M[0].y - (M[2].x*M[2].x + M[2].y*M[2].y);
            mm[1] = M[1].x*M[1].x + M[1].y*M[1].y - (M[3].x*M[3].x + M[3].y*M[3].y);
            mm[2] = (M[0].x*M[1].x + M[0].y*M[1].y) - (M[2].x*M[3].x + M[2].y*M[3].y);
            mm[3] = (M[0].x*M[1].y - M[0].y*M[1].x) - (M[2].x*M[3].y - M[2].y*M[3].x);
        }
    }
}

// bank swizzle on 13-bit idx; GF(2)-LINEAR
__device__ inline constexpr uint32_t slotf(uint32_t i){
    return i ^ (((i>>4) ^ (i>>8) ^ (i>>12)) & 15u);
}
template<int B> __device__ inline constexpr uint32_t ins0(uint32_t t){
    return ((t & ~((1u<<B)-1u)) << 1) | (t & ((1u<<B)-1u));
}
// deposit t's 11 bits into complement of idx bits X0<X1
template<int X0,int X1> __device__ inline constexpr uint32_t expand2(uint32_t t){
    return ins0<X1>(ins0<X0>(t));
}
template<int X0,int X1> __device__ inline constexpr uint32_t rmask2(int r){
    return ((r&1)?(1u<<X0):0u) | ((r&2)?(1u<<X1):0u);
}

// ---- gate primitives on slab-SoA state: vr/vi[4] v2f, lanes = (q13=0, q13=1) ----
// rotation on window-local bit J (J=0 -> idx X0, J=1 -> idx X1): pure
// elementwise scalar-broadcast x v2f: clang emits v_pk_fma_f32, no shuffles.
template<int J>
__device__ inline void rotW(v2f* vr, v2f* vi, const float* __restrict__ g){
    const float are=g[0], aim=g[1], bre=g[2], bim=g[3];
    const float cre=g[4], cim=g[5], dre=g[6], dim=g[7];
    #pragma unroll
    for (int r = 0; r < 4; ++r){
        if (!(r & (1 << J))) {
            const int r1 = r | (1 << J);
            v2f x0r = vr[r],  x0i = vi[r];
            v2f x1r = vr[r1], x1i = vi[r1];
            vr[r]  = are*x0r - aim*x0i + bre*x1r - bim*x1i;
            vi[r]  = are*x0i + aim*x0r + bre*x1i + bim*x1r;
            vr[r1] = cre*x0r - cim*x0i + dre*x1r - dim*x1i;
            vi[r1] = cre*x0i + cim*x0r + dre*x1i + dim*x1r;
        }
    }
}
// rotation on q13 (the lane dimension): scalar math across the 2 lane-regs
__device__ inline void rotLane(v2f* vr, v2f* vi, const float* __restrict__ g){
    const float are=g[0], aim=g[1], bre=g[2], bim=g[3];
    const float cre=g[4], cim=g[5], dre=g[6], dim=g[7];
    #pragma unroll
    for (int r = 0; r < 4; ++r){
        float x0r = vr[r].x, x0i = vi[r].x, x1r = vr[r].y, x1i = vi[r].y;
        vr[r].x = are*x0r - aim*x0i + bre*x1r - bim*x1i;
        vi[r].x = are*x0i + aim*x0r + bre*x1i + bim*x1r;
        vr[r].y = cre*x0r - cim*x0i + dre*x1r - dim*x1i;
        vi[r].y = cre*x0i + cim*x0r + dre*x1i + dim*x1r;
    }
}
// CNOT both window bits: register renaming
template<int C, int T>
__device__ inline void cnotW(v2f* vr, v2f* vi){
    #pragma unroll
    for (int r = 0; r < 4; ++r){
        if ((r & (1 << C)) && !(r & (1 << T))) {
            const int r1 = r | (1 << T);
            v2f t0 = vr[r]; vr[r] = vr[r1]; vr[r1] = t0;
            v2f t1 = vi[r]; vi[r] = vi[r1]; vi[r1] = t1;
        }
    }
}
// CNOT ctl = tid bit (uniform), tgt = window bit T: cndmask
template<int T>
__device__ inline void cnotSelW(v2f* vr, v2f* vi, bool c){
    #pragma unroll
    for (int r = 0; r < 4; ++r){
        if (!(r & (1 << T))) {
            const int r1 = r | (1 << T);
            v2f l0 = vr[r], h0 = vr[r1], l1 = vi[r], h1 = vi[r1];
            vr[r] = c ? h0 : l0;  vr[r1] = c ? l0 : h0;
            vi[r] = c ? h1 : l1;  vi[r1] = c ? l1 : h1;
        }
    }
}
// CN(12,13): ctl = window bit0 (q12), tgt = lane (q13): lane swap where r&1
__device__ inline void cnotRegLane(v2f* vr, v2f* vi){
    #pragma unroll
    for (int r = 0; r < 4; ++r){
        if (r & 1) { vr[r] = vr[r].yx; vi[r] = vi[r].yx; }
    }
}
// CN(13,0): ctl = lane (q13), tgt = window bit1 (q0): swap .y halves of r<->r|2
__device__ inline void cnotLaneReg(v2f* vr, v2f* vi){
    #pragma unroll
    for (int r = 0; r < 2; ++r){
        const int r1 = r | 2;
        float t0 = vr[r].y; vr[r].y = vr[r1].y; vr[r1].y = t0;
        float t1 = vi[r].y; vi[r].y = vi[r1].y; vi[r1].y = t1;
    }
}

__global__ __launch_bounds__(BLK) void qsim_kernel(
        const float* __restrict__ xr, const float* __restrict__ xi,
        const float* __restrict__ gg, float* __restrict__ out) {
    // slab-SoA LDS: planes over 13-bit idx; v2f lanes = (b0=0, b0=1) = q13
    __shared__ v2f sre[HDIM];         // 64 KiB
    __shared__ v2f sim[HDIM];         // 64 KiB
    __shared__ float red[BLK / 64];

    const int b   = blockIdx.x;
    const uint32_t tid = threadIdx.x;

    const float* xrb = xr + (size_t)b * DIM;
    const float* xib = xi + (size_t)b * DIM;

    // qubit q <-> amp bit (13-q); idx = amp>>1. coefficients: uniform global
    #define GMP(li, q) (&gg[((li) * NQ + (q)) * 8])

    // One pass: 2 sequential slabs; live state = vr[4]+vi[4] = 16 VGPRs.
    #define PASS(X0, X1, ...)                                                      \
        _Pragma("unroll 1")                                                        \
        for (uint32_t sl = 0; sl < 2; ++sl) {                                      \
            const uint32_t t  = tid + sl * BLK;                                    \
            const uint32_t sb = slotf(expand2<X0,X1>(t));                          \
            v2f vr[4], vi[4];                                                      \
            _Pragma("unroll")                                                      \
            for (int r = 0; r < 4; ++r) {                                          \
                const uint32_t a = sb ^ slotf(rmask2<X0,X1>(r));                   \
                vr[r] = sre[a]; vi[r] = sim[a];                                    \
            }                                                                      \
            __VA_ARGS__                                                            \
            _Pragma("unroll")                                                      \
            for (int r = 0; r < 4; ++r) {                                          \
                const uint32_t a = sb ^ slotf(rmask2<X0,X1>(r));                   \
                sre[a] = vr[r]; sim[a] = vi[r];                                    \
            }                                                                      \
        }                                                                          \
        __syncthreads();

    float local = 0.f;

    // ---- 4 ring layers x 7 two-qubit windows; L5 absorbed into meas ----
    // W1(idx11,12)=(q1,q0): rot q0(b1),q1(b0) + CN(0,1)
    // W2(idx9,10)=(q3,q2):  rot q2(b1),q3(b0) + selCN(1,2)[t9] + CN(2,3)
    // W3(idx7,8)=(q5,q4):   rot q4(b1),q5(b0) + selCN(3,4)[t7] + CN(4,5)
    // W4(idx5,6)=(q7,q6):   rot q6(b1),q7(b0) + selCN(5,6)[t5] + CN(6,7)
    // W5(idx3,4)=(q9,q8):   rot q8(b1),q9(b0) + selCN(7,8)[t3] + CN(8,9)
    // W6(idx1,2)=(q11,q10): rot q10(b1),q11(b0) + selCN(9,10)[t1] + CN(10,11)
    // W7(idx0,12)=(q12,q0), q13=lane: rot q12(b0), rotLane q13,
    //   selCN(11,12)[t0,tgt b0] + CN(12,13)[ctl b0,tgt lane] + CN(13,0)[ctl lane,tgt b1]
    //   (li==3: fuse M1 quadratic form on q0 = bit1 pairs, no scatter)
    #pragma unroll 1
    for (int li = 0; li < 4; ++li) {
        // ---- W1 (idx 11,12): local bit0=idx11(q1), bit1=idx12(q0) ----
        #pragma unroll 1
        for (uint32_t sl = 0; sl < 2; ++sl) {
            const uint32_t t = tid + sl * BLK;
            v2f vr[4], vi[4];
            if (li == 0) {
                // expand2<11,12>(t) = t; amp = (idx)<<1 | lane -> float2 loads
                #pragma unroll
                for (int r = 0; r < 4; ++r) {
                    const uint32_t a2 = (t | rmask2<11,12>(r)) << 1;
                    float2 fr = *(const float2*)&xrb[a2];
                    float2 fi = *(const float2*)&xib[a2];
                    vr[r] = v2f{fr.x, fr.y}; vi[r] = v2f{fi.x, fi.y};
                }
            } else {
                const uint32_t sb = slotf(expand2<11,12>(t));
                #pragma unroll
                for (int r = 0; r < 4; ++r) {
                    const uint32_t a = sb ^ slotf(rmask2<11,12>(r));
                    vr[r] = sre[a]; vi[r] = sim[a];
                }
            }
            rotW<1>(vr, vi, GMP(li,0));    // q0 = idx12 = bit1
            rotW<0>(vr, vi, GMP(li,1));    // q1 = idx11 = bit0
            cnotW<1,0>(vr, vi);            // CN(0,1)
            const uint32_t sb = slotf(expand2<11,12>(t));
            #pragma unroll
            for (int r = 0; r < 4; ++r) {
                const uint32_t a = sb ^ slotf(rmask2<11,12>(r));
                sre[a] = vr[r]; sim[a] = vi[r];
            }
        }
        __syncthreads();

        // ---- W2 (idx 9,10): bit0=idx9(q3), bit1=idx10(q2) ----
        PASS(9,10,
            rotW<1>(vr, vi, GMP(li,2));
            rotW<0>(vr, vi, GMP(li,3));
            cnotSelW<1>(vr, vi, (tid >> 9) & 1u);   // CN(1,2): ctl q1=idx11=t9
            cnotW<1,0>(vr, vi);                     // CN(2,3)
        )
        // ---- W3 (idx 7,8): bit0=idx7(q5), bit1=idx8(q4) ----
        PASS(7,8,
            rotW<1>(vr, vi, GMP(li,4));
            rotW<0>(vr, vi, GMP(li,5));
            cnotSelW<1>(vr, vi, (tid >> 7) & 1u);   // CN(3,4): ctl q3=idx9=t7
            cnotW<1,0>(vr, vi);                     // CN(4,5)
        )
        // ---- W4 (idx 5,6): bit0=idx5(q7), bit1=idx6(q6) ----
        PASS(5,6,
            rotW<1>(vr, vi, GMP(li,6));
            rotW<0>(vr, vi, GMP(li,7));
            cnotSelW<1>(vr, vi, (tid >> 5) & 1u);   // CN(5,6): ctl q5=idx7=t5
            cnotW<1,0>(vr, vi);                     // CN(6,7)
        )
        // ---- W5 (idx 3,4): bit0=idx3(q9), bit1=idx4(q8) ----
        PASS(3,4,
            rotW<1>(vr, vi, GMP(li,8));
            rotW<0>(vr, vi, GMP(li,9));
            cnotSelW<1>(vr, vi, (tid >> 3) & 1u);   // CN(7,8): ctl q7=idx5=t3
            cnotW<1,0>(vr, vi);                     // CN(8,9)
        )
        // ---- W6 (idx 1,2): bit0=idx1(q11), bit1=idx2(q10) ----
        PASS(1,2,
            rotW<1>(vr, vi, GMP(li,10));
            rotW<0>(vr, vi, GMP(li,11));
            cnotSelW<1>(vr, vi, (tid >> 1) & 1u);   // CN(9,10): ctl q9=idx3=t1
            cnotW<1,0>(vr, vi);                     // CN(10,11)
        )
        // ---- W7 (idx 0,12): bit0=idx0(q12), bit1=idx12(q0), lane=q13 ----
        #pragma unroll 1
        for (uint32_t sl = 0; sl < 2; ++sl) {
            const uint32_t t  = tid + sl * BLK;
            const uint32_t sb = slotf(expand2<0,12>(t));
            v2f vr[4], vi[4];
            #pragma unroll
            for (int r = 0; r < 4; ++r) {
                const uint32_t a = sb ^ slotf(rmask2<0,12>(r));
                vr[r] = sre[a]; vi[r] = sim[a];
            }
            rotW<0>(vr, vi, GMP(li,12));            // q12 = idx0 = bit0
            rotLane(vr, vi, GMP(li,13));            // q13 = lane
            cnotSelW<0>(vr, vi, tid & 1u);          // CN(11,12): ctl q11=idx1=t0
            cnotRegLane(vr, vi);                    // CN(12,13)
            cnotLaneReg(vr, vi);                    // CN(13,0)
            if (li < 3) {
                #pragma unroll
                for (int r = 0; r < 4; ++r) {
                    const uint32_t a = sb ^ slotf(rmask2<0,12>(r));
                    sre[a] = vr[r]; sim[a] = vi[r];
                }
            } else {
                const float* mm = &gg[5 * NQ * 8];
                const float mA = mm[0], mB = mm[1], mP = mm[2], mQ = mm[3];
                v2f acc = v2f{0.f, 0.f};
                #pragma unroll
                for (int r = 0; r < 2; ++r) {
                    const int r1 = r | 2;               // q0=1 partner
                    v2f x0r = vr[r],  x0i = vi[r];
                    v2f x1r = vr[r1], x1i = vi[r1];
                    v2f n0 = x0r*x0r + x0i*x0i;
                    v2f n1 = x1r*x1r + x1i*x1i;
                    v2f u  = x0r*x1r + x0i*x1i;         // Re(conj(a0) a1)
                    v2f vv = x0r*x1i - x0i*x1r;         // Im(conj(a0) a1)
                    acc += mA*n0 + mB*n1 + 2.f*(mP*u - mQ*vv);
                }
                local += acc.x + acc.y;
            }
        }
        if (li < 3) __syncthreads();
    }

    #pragma unroll
    for (int off = 32; off > 0; off >>= 1) local += __shfl_down(local, off);
    const int lane = tid & 63, wid = tid >> 6;
    if (lane == 0) red[wid] = local;
    __syncthreads();
    if (tid == 0) {
        float t = 0.f;
        #pragma unroll
        for (int k = 0; k < BLK / 64; ++k) t += red[k];
        out[b] = t;
    }
}

extern "C" void kernel_launch(void* const* d_in, const int* in_sizes, int n_in,
                              void* d_out, int out_size, void* d_ws, size_t ws_size,
                              hipStream_t stream) {
    const float* xr = (const float*)d_in[0];
    const float* xi = (const float*)d_in[1];
    const float* w  = (const float*)d_in[2];
    float* out = (float*)d_out;
    float* gg = (float*)d_ws;   // 70 gates x 8 floats + 4 floats meas = 2256 B
    const int B = out_size;     // 512
    prep_kernel<<<1, 128, 0, stream>>>(w, gg);
    qsim_kernel<<<B, BLK, 0, stream>>>(xr, xi, gg, out);
}

// Round 21
// 109.656 us; speedup vs baseline: 1.3456x; 1.1589x over previous
//
#include <hip/hip_runtime.h>
#include <hip/hip_bf16.h>

#define NQ   14
#define DIM  16384      // 2^14
#define BLK  1024
#define WMUL 0.6324555320336759f  // sqrt(2/5)

typedef float v2f __attribute__((ext_vector_type(2)));

struct C2 { float x, y; };  // build-time only
__device__ inline C2 cmulc(C2 a, C2 b){ return C2{a.x*b.x - a.y*b.y, a.x*b.y + a.y*b.x}; }
__device__ inline C2 caddc(C2 a, C2 b){ return C2{a.x+b.x, a.y+b.y}; }
__device__ inline void mm2(const C2* a, const C2* b, C2* o) {
    o[0] = caddc(cmulc(a[0],b[0]), cmulc(a[1],b[2]));
    o[1] = caddc(cmulc(a[0],b[1]), cmulc(a[1],b[3]));
    o[2] = caddc(cmulc(a[2],b[0]), cmulc(a[3],b[2]));
    o[3] = caddc(cmulc(a[2],b[1]), cmulc(a[3],b[3]));
}
__device__ inline void build_gate(int ty, float t, C2* g) {
    float sn, cs;
    __sincosf(0.5f * t, &sn, &cs);
    if (ty == 0) {        // rx
        g[0] = C2{cs, 0.f}; g[1] = C2{0.f, -sn};
        g[2] = C2{0.f, -sn}; g[3] = C2{cs, 0.f};
    } else if (ty == 1) { // ry
        g[0] = C2{cs, 0.f}; g[1] = C2{-sn, 0.f};
        g[2] = C2{sn, 0.f}; g[3] = C2{cs, 0.f};
    } else {              // rz
        g[0] = C2{cs, -sn}; g[1] = C2{0.f, 0.f};
        g[2] = C2{0.f, 0.f}; g[3] = C2{cs, sn};
    }
}
__device__ const int TYPES[5][3] = {
    {0,1,2},  // XYZ
    {1,2,1},  // YZY
    {2,1,0},  // ZYX
    {0,2,0},  // XZX
    {1,2,1},  // YZY
};

// ---- prep kernel: 70 fused gates (packed form) + absorbed observable -> d_ws.
// Gates are batch-independent: compute ONCE, not per block. Main kernel reads
// them via wave-uniform global addresses (L2-resident, no LDS traffic).
__global__ void prep_kernel(const float* __restrict__ w, v2f* __restrict__ gg) {
    const int tid = threadIdx.x;
    if (tid < 5 * NQ) {
        const int li = tid / NQ, q = tid % NQ;
        C2 M[4], G[4], T[4];
        #pragma unroll
        for (int j = 0; j < 3; ++j) {
            float t = w[3 * NQ * li + 3 * q + j] * WMUL;
            build_gate(TYPES[li][j], t, G);
            if (j == 0) { M[0]=G[0]; M[1]=G[1]; M[2]=G[2]; M[3]=G[3]; }
            else { mm2(G, M, T); M[0]=T[0]; M[1]=T[1]; M[2]=T[2]; M[3]=T[3]; }
        }
        v2f* gb = &gg[tid * 8];
        #pragma unroll
        for (int k = 0; k < 4; ++k) {
            gb[k * 2 + 0] = v2f{ M[k].x, M[k].x};
            gb[k * 2 + 1] = v2f{-M[k].y, M[k].y};
        }
        // absorbed observable M1 = M† Z M for the layer-5 qubit-0 rotation
        if (tid == 4 * NQ + 0) {
            float* mm = (float*)&gg[5 * NQ * 8];
            mm[0] = M[0].x*M[0].x + M[0].y*M[0].y - (M[2].x*M[2].x + M[2].y*M[2].y);
            mm[1] = M[1].x*M[1].x + M[1].y*M[1].y - (M[3].x*M[3].x + M[3].y*M[3].y);
            mm[2] = (M[0].x*M[1].x + M[0].y*M[1].y) - (M[2].x*M[3].x + M[2].y*M[3].y);
            mm[3] = (M[0].x*M[1].y - M[0].y*M[1].x) - (M[2].x*M[3].y - M[2].y*M[3].x);
        }
    }
}

// bank-conflict swizzle; GF(2)-LINEAR: slotf(a|b) = slotf(a)^slotf(b) for disjoint a,b
__device__ inline constexpr uint32_t slotf(uint32_t i){
    return i ^ (((i>>4) ^ (i>>8) ^ (i>>12)) & 15u);
}
template<int B> __device__ inline uint32_t ins0(uint32_t t){
    return ((t & ~((1u<<B)-1u)) << 1) | (t & ((1u<<B)-1u));
}
template<int B0,int B1,int B2> __device__ inline uint32_t expand3(uint32_t t){
    return ins0<B2>(ins0<B1>(ins0<B0>(t)));
}
template<int B0,int B1,int B2> __device__ inline constexpr uint32_t rmask3(int r){
    return ((r&1)?(1u<<B0):0u) | ((r&2)?(1u<<B1):0u) | ((r&4)?(1u<<B2):0u);
}

// packed rotation on local bit J. g = wave-uniform global pointer (prep output).
template<int J>
__device__ inline void rot8(v2f* v, const v2f* __restrict__ g){
    const v2f a00=g[0], b00=g[1], a01=g[2], b01=g[3];
    const v2f a10=g[4], b10=g[5], a11=g[6], b11=g[7];
    #pragma unroll
    for (int r = 0; r < 8; ++r){
        if (!(r & (1 << J))) {
            v2f x0 = v[r], x1 = v[r | (1 << J)];
            v2f s0 = x0.yx, s1 = x1.yx;
            v2f y0 = a00*x0 + b00*s0 + a01*x1 + b01*s1;
            v2f y1 = a10*x0 + b10*s0 + a11*x1 + b11*s1;
            v[r] = y0; v[r | (1<<J)] = y1;
        }
    }
}
// CNOT both-in-reg: control bit C, target bit T (register renaming, free)
template<int C, int T>
__device__ inline void cnot8(v2f* v){
    #pragma unroll
    for (int r = 0; r < 8; ++r){
        if ((r & (1 << C)) && !(r & (1 << T))) {
            v2f tt = v[r]; v[r] = v[r | (1 << T)]; v[r | (1 << T)] = tt;
        }
    }
}
// CNOT with control = thread-index bit, target reg bit T: pure v_cndmask
template<int T>
__device__ inline void cnotSel(v2f* v, bool c){
    #pragma unroll
    for (int r = 0; r < 8; ++r){
        if (!(r & (1 << T))) {
            v2f lo = v[r], hi = v[r | (1 << T)];
            v[r]          = c ? hi : lo;
            v[r | (1<<T)] = c ? lo : hi;
        }
    }
}

__global__ __launch_bounds__(BLK) void qsim_kernel(
        const float* __restrict__ xr, const float* __restrict__ xi,
        const v2f* __restrict__ gg, float* __restrict__ out) {
    __shared__ v2f s[DIM];            // 128 KiB statevector (swizzled layout)
    __shared__ float red[BLK / 64];

    const int b   = blockIdx.x;
    const uint32_t tid = threadIdx.x;

    const float* xrb = xr + (size_t)b * DIM;
    const float* xib = xi + (size_t)b * DIM;

    // qubit q <-> bit (13-q).  coefficients: uniform global (prep kernel output)
    #define GMP(li, q) (&gg[((li) * NQ + (q)) * 8])

    // One pass: 2 sequential slabs (live state = v2f v[8] = 16 VGPRs).
    #define PASS(B0, B1, B2, ...)                                                  \
        _Pragma("unroll 1")                                                        \
        for (uint32_t sl = 0; sl < 2; ++sl) {                                      \
            const uint32_t t  = tid + sl * BLK;                                    \
            const uint32_t sb = slotf(expand3<B0,B1,B2>(t));                       \
            v2f v[8];                                                              \
            _Pragma("unroll")                                                      \
            for (int r = 0; r < 8; ++r)                                            \
                v[r] = s[sb ^ slotf(rmask3<B0,B1,B2>(r))];                         \
            __VA_ARGS__                                                            \
            _Pragma("unroll")                                                      \
            for (int r = 0; r < 8; ++r)                                            \
                s[sb ^ slotf(rmask3<B0,B1,B2>(r))] = v[r];                         \
        }                                                                          \
        __syncthreads();

    float local = 0.f;

    // ---- 4 ring layers, 5 non-overlapping windows each; L5 absorbed in meas ----
    // A(11,12,13): rot q0,q1,q2 + CN(0,1),(1,2)
    // B(8,9,10):   rot q3,q4,q5 + CN(2,3)[sel ctl=t8] + CN(3,4),(4,5)
    // C(5,6,7):    rot q6,q7,q8 + CN(5,6)[sel ctl=t5] + CN(6,7),(7,8)
    // D(2,3,4):    rot q9,q10,q11 + CN(8,9)[sel ctl=t2] + CN(9,10),(10,11)
    // E(0,1,13):   rot q12,q13 + CN(11,12)[sel ctl=t0] + CN(12,13),(13,0)
    //              (li==3: fuse M1 quadratic form on b13 = L2 pairs, no scatter)
    #pragma unroll 1
    for (int li = 0; li < 4; ++li) {
        // ---- A (11,12,13) ----
        #pragma unroll 1
        for (uint32_t sl = 0; sl < 2; ++sl) {
            const uint32_t t = tid + sl * BLK;
            v2f v[8];
            if (li == 0) {
                #pragma unroll
                for (int r = 0; r < 8; ++r) {
                    uint32_t i = t | ((uint32_t)r << 11);   // expand3<11,12,13>(t)=t
                    v[r] = v2f{xrb[i], xib[i]};
                }
            } else {
                const uint32_t sb = slotf(expand3<11,12,13>(t));
                #pragma unroll
                for (int r = 0; r < 8; ++r)
                    v[r] = s[sb ^ slotf(rmask3<11,12,13>(r))];
            }
            rot8<2>(v, GMP(li,0)); rot8<1>(v, GMP(li,1)); rot8<0>(v, GMP(li,2));
            cnot8<2,1>(v); cnot8<1,0>(v);                  // CN(0,1),(1,2)
            const uint32_t sb = slotf(expand3<11,12,13>(t));
            #pragma unroll
            for (int r = 0; r < 8; ++r)
                s[sb ^ slotf(rmask3<11,12,13>(r))] = v[r];
        }
        __syncthreads();

        // ---- B (8,9,10): rot q3(b10),q4(b9),q5(b8) ----
        PASS(8,9,10,
            rot8<2>(v, GMP(li,3)); rot8<1>(v, GMP(li,4)); rot8<0>(v, GMP(li,5));
            cnotSel<2>(v, (t >> 8) & 1u);                  // CN(2,3): ctl q2=b11
            cnot8<2,1>(v); cnot8<1,0>(v);                  // CN(3,4),(4,5)
        )
        // ---- C (5,6,7): rot q6(b7),q7(b6),q8(b5) ----
        PASS(5,6,7,
            rot8<2>(v, GMP(li,6)); rot8<1>(v, GMP(li,7)); rot8<0>(v, GMP(li,8));
            cnotSel<2>(v, (t >> 5) & 1u);                  // CN(5,6): ctl q5=b8
            cnot8<2,1>(v); cnot8<1,0>(v);                  // CN(6,7),(7,8)
        )
        // ---- D (2,3,4): rot q9(b4),q10(b3),q11(b2) ----
        PASS(2,3,4,
            rot8<2>(v, GMP(li,9)); rot8<1>(v, GMP(li,10)); rot8<0>(v, GMP(li,11));
            cnotSel<2>(v, (t >> 2) & 1u);                  // CN(8,9): ctl q8=b5
            cnot8<2,1>(v); cnot8<1,0>(v);                  // CN(9,10),(10,11)
        )
        // ---- E (0,1,13): rot q12(b1=L1),q13(b0=L0) ----
        #pragma unroll 1
        for (uint32_t sl = 0; sl < 2; ++sl) {
            const uint32_t t  = tid + sl * BLK;
            const uint32_t sb = slotf(expand3<0,1,13>(t));
            v2f v[8];
            #pragma unroll
            for (int r = 0; r < 8; ++r)
                v[r] = s[sb ^ slotf(rmask3<0,1,13>(r))];
            rot8<1>(v, GMP(li,12)); rot8<0>(v, GMP(li,13));
            cnotSel<1>(v, t & 1u);                         // CN(11,12): ctl q11=b2
            cnot8<1,0>(v);                                 // CN(12,13)
            cnot8<0,2>(v);                                 // CN(13,0)
            if (li < 3) {
                #pragma unroll
                for (int r = 0; r < 8; ++r)
                    s[sb ^ slotf(rmask3<0,1,13>(r))] = v[r];
            } else {
                const float* mm = (const float*)&gg[5 * NQ * 8];
                const float mA = mm[0], mB = mm[1], mP = mm[2], mQ = mm[3];
                #pragma unroll
                for (int r = 0; r < 4; ++r) {
                    v2f a0 = v[r], a1 = v[r | 4];          // b13=0 / b13=1
                    float n0 = a0.x*a0.x + a0.y*a0.y;
                    float n1 = a1.x*a1.x + a1.y*a1.y;
                    float u  = a0.x*a1.x + a0.y*a1.y;      // Re(conj(a0) a1)
                    float vv = a0.x*a1.y - a0.y*a1.x;      // Im(conj(a0) a1)
                    local += mA*n0 + mB*n1 + 2.f*(mP*u - mQ*vv);
                }
            }
        }
        if (li < 3) __syncthreads();
    }

    #pragma unroll
    for (int off = 32; off > 0; off >>= 1) local += __shfl_down(local, off);
    const int lane = tid & 63, wid = tid >> 6;
    if (lane == 0) red[wid] = local;
    __syncthreads();
    if (tid == 0) {
        float t = 0.f;
        #pragma unroll
        for (int k = 0; k < BLK / 64; ++k) t += red[k];
        out[b] = t;
    }
}

extern "C" void kernel_launch(void* const* d_in, const int* in_sizes, int n_in,
                              void* d_out, int out_size, void* d_ws, size_t ws_size,
                              hipStream_t stream) {
    const float* xr = (const float*)d_in[0];
    const float* xi = (const float*)d_in[1];
    const float* w  = (const float*)d_in[2];
    float* out = (float*)d_out;
    v2f* gg = (v2f*)d_ws;     // 70 gates x 8 v2f + 4 floats meas = 4496 B
    const int B = out_size;   // 512
    prep_kernel<<<1, 128, 0, stream>>>(w, gg);
    qsim_kernel<<<B, BLK, 0, stream>>>(xr, xi, gg, out);
}